// Round 11
// baseline (446.498 us; speedup 1.0000x reference)
//
#include <hip/hip_runtime.h>
#include <hip/hip_bf16.h>

// QuantizedLinear: out[M,N] = inp[M,K] @ (qw[N,K] * scale[N])^T
// M = 4096, K = 4096, N = 12288.
// Round 11: NO-LDS free-running i8 GEMM.
//   Pass 1a: per-row absmax-quantize A fp32 -> int8, written directly in
//            MFMA A-fragment order (chunk = ((r64*32+kt)*4+mf)*2+ks, lane*16).
//   Pass 1b: W int32 -> int8 packed in B-fragment order
//            (chunk = (n16*32+kt)*2+ks, lane*16).
//   Pass 2:  GEMM with zero LDS / zero barriers / zero asm waits: fragments
//            stream L2->regs coalesced (1KB per load instr); compiler
//            software-pipelines freely; 64x32 wave tile keeps regs <=128
//            (__launch_bounds__(512,4)) -> 4 waves/SIMD, free-running.
//            L1 dedups A across the 4 wn-waves and B across 2 wm-waves.
//   Epilogue: out = (float)acc * scale_w[col] * Ra[row].

#define K_DIM 4096
#define N_DIM 12288

constexpr int BM = 128;           // block tile M (2 wm-waves x 64)
constexpr int BN = 128;           // block tile N (4 wn-waves x 32)
constexpr int NT = K_DIM / 128;   // 32 K-tiles of 128 i8

typedef float  f32x4  __attribute__((ext_vector_type(4)));
typedef int    i32x4  __attribute__((ext_vector_type(4)));
typedef short  bf16x8 __attribute__((ext_vector_type(8)));
typedef unsigned short u16x4 __attribute__((ext_vector_type(4)));

__device__ __forceinline__ unsigned short f32_to_bf16(float f) {
    unsigned int u = __builtin_bit_cast(unsigned int, f);
    u += 0x7FFFu + ((u >> 16) & 1u);
    return (unsigned short)(u >> 16);
}

// ---------------- Pass 1a: quantize A -> int8, packed in A-frag order -------
// Fragment mapping (validated r8-r10): lane l holds A[m][k], m-part = l&15,
// k-group = (l>>4)*16. Chunk (r64, kt, mf, ks), 1KB each:
//   lane l bytes = Aq8[r64*64 + mf*16 + (l&15)][kt*128 + ks*64 + (l>>4)*16 ..+16)
// One block per row; thread tid owns 16B chunk k16 = tid.

__global__ __launch_bounds__(256)
void quant_a_pack(const float* __restrict__ A,
                  signed char* __restrict__ Apk,
                  float* __restrict__ Ra) {
    const int row  = blockIdx.x;
    const int tid  = threadIdx.x;
    const int lane = tid & 63;
    const int wid  = tid >> 6;
    const float* arow = A + (size_t)row * K_DIM;
    const int base = tid * 16;

    f32x4 v[4];
    #pragma unroll
    for (int i = 0; i < 4; ++i)
        v[i] = *(const f32x4*)(arow + base + i * 4);

    float mx = 0.f;
    #pragma unroll
    for (int i = 0; i < 4; ++i)
        #pragma unroll
        for (int j = 0; j < 4; ++j)
            mx = fmaxf(mx, fabsf(v[i][j]));

    #pragma unroll
    for (int off = 32; off > 0; off >>= 1)
        mx = fmaxf(mx, __shfl_xor(mx, off));

    __shared__ float wmax[4];
    if (lane == 0) wmax[wid] = mx;
    __syncthreads();
    mx = fmaxf(fmaxf(wmax[0], wmax[1]), fmaxf(wmax[2], wmax[3]));

    const float inv = (mx > 0.f) ? (127.0f / mx) : 0.f;
    if (tid == 0) Ra[row] = mx * (1.0f / 127.0f);

    int p[4];
    #pragma unroll
    for (int i = 0; i < 4; ++i) {
        int b0 = (int)rintf(v[i][0] * inv);
        int b1 = (int)rintf(v[i][1] * inv);
        int b2 = (int)rintf(v[i][2] * inv);
        int b3 = (int)rintf(v[i][3] * inv);
        p[i] = (b0 & 255) | ((b1 & 255) << 8) | ((b2 & 255) << 16) | (b3 << 24);
    }

    // packed destination for this (row, k16) 16B chunk
    const int k16  = tid;
    const int kt   = k16 >> 3;            // 0..31
    const int ks   = (k16 >> 2) & 1;      // 0..1
    const int hi   = k16 & 3;             // (l>>4)
    const int ln   = hi * 16 + (row & 15);
    const int mf   = (row >> 4) & 3;
    const int r64  = row >> 6;
    const size_t off = (((((size_t)r64 * 32 + kt) * 4 + mf) * 2 + ks) << 10) + ln * 16;
    *(i32x4*)(Apk + off) = *(i32x4*)p;
}

// ---------------- Pass 1b: W int32 -> int8 packed in B-frag order ----------
// chunk = (n16*32 + kt)*2 + ks; lane l bytes =
//   W8[n16*16 + (l&15)][kt*128 + ks*64 + (l>>4)*16 ..+16)

__global__ __launch_bounds__(256)
void pack_w_kernel(const int* __restrict__ W, signed char* __restrict__ Wpk, int nchunk) {
    int stride = gridDim.x * blockDim.x;
    for (int gid = blockIdx.x * blockDim.x + threadIdx.x; gid < nchunk; gid += stride) {
        const int l   = gid & 63;
        const int blk = gid >> 6;
        const int ks  = blk & 1;
        const int kt  = (blk >> 1) & 31;
        const int n16 = blk >> 6;
        const int n   = n16 * 16 + (l & 15);
        const int kb  = kt * 128 + ks * 64 + ((l >> 4) * 16);
        const int* src = W + (size_t)n * K_DIM + kb;
        int p[4];
        #pragma unroll
        for (int q = 0; q < 4; ++q) {
            const i32x4 w = *(const i32x4*)(src + q * 4);
            p[q] = (w[0] & 255) | ((w[1] & 255) << 8) | ((w[2] & 255) << 16) | (w[3] << 24);
        }
        *(i32x4*)(Wpk + (size_t)gid * 16) = *(i32x4*)p;
    }
}

// ---------------- Pass 2: no-LDS free-running i8 GEMM ----------------

__global__ __launch_bounds__(512, 4)
void gemm_i8_nolds(const signed char* __restrict__ Apk,  // packed A frags
                   const signed char* __restrict__ Wpk,  // packed B frags
                   const float* __restrict__ Sw,         // [N]
                   const float* __restrict__ Ra,         // [M]
                   float* __restrict__ Out,              // [M,N]
                   int M) {
    const int tid  = threadIdx.x;
    const int lane = tid & 63;
    const int wid  = tid >> 6;          // 0..7
    const int wm   = wid >> 2;          // 0..1  (64-row half)
    const int wn   = wid & 3;           // 0..3  (32-col strip)

    // T1: XCD swizzle (3072 blocks, 384/XCD), column-major within chunk
    const int nwgy = M / BM;                 // 32
    const int nwg  = (N_DIM / BN) * nwgy;    // 3072
    const int cpx  = nwg >> 3;               // 384
    const int bid  = blockIdx.x;
    const int swz  = (bid & 7) * cpx + (bid >> 3);
    const int bx   = swz / nwgy;
    const int by   = swz % nwgy;
    const int bm   = by * BM;
    const int bn   = bx * BN;

    const int r64     = by * 2 + wm;         // A 64-row block index
    const int n16base = bx * 8 + wn * 2;     // B 16-col block index

    // chunk bases (each chunk 1KB; lane offset fixed)
    const signed char* Ab = Apk + (((size_t)r64) << 18) + lane * 16;   // 256 chunks/r64
    const signed char* Bb = Wpk + (((size_t)n16base) << 16) + lane * 16; // 64 chunks/n16

    i32x4 acc[4][2];
    #pragma unroll
    for (int i = 0; i < 4; ++i)
        #pragma unroll
        for (int j = 0; j < 2; ++j)
            acc[i][j] = (i32x4){0, 0, 0, 0};

    for (int kt = 0; kt < NT; ++kt) {
        i32x4 af[4][2];   // 4 m-frags x 2 k-slices
        i32x4 bf[2][2];   // 2 n-frags x 2 k-slices
        #pragma unroll
        for (int mf = 0; mf < 4; ++mf)
            #pragma unroll
            for (int ks = 0; ks < 2; ++ks)
                af[mf][ks] = *(const i32x4*)(Ab + (((size_t)(kt * 8 + mf * 2 + ks)) << 10));
        #pragma unroll
        for (int nf = 0; nf < 2; ++nf)
            #pragma unroll
            for (int ks = 0; ks < 2; ++ks)
                bf[nf][ks] = *(const i32x4*)(Bb + (((size_t)(nf * 64 + kt * 2 + ks)) << 10));

        __builtin_amdgcn_s_setprio(1);
        #pragma unroll
        for (int ks = 0; ks < 2; ++ks)
            #pragma unroll
            for (int mf = 0; mf < 4; ++mf)
                #pragma unroll
                for (int nf = 0; nf < 2; ++nf)
                    acc[mf][nf] = __builtin_amdgcn_mfma_i32_16x16x64_i8(
                        af[mf][ks], bf[nf][ks], acc[mf][nf], 0, 0, 0);
        __builtin_amdgcn_s_setprio(0);
    }

    // ---- epilogue: C/D col = lane&15 (B idx), row = (lane>>4)*4 + j ----
    const int c0 = lane & 15;
    const int r0 = (lane >> 4) * 4;
    #pragma unroll
    for (int nf = 0; nf < 2; ++nf) {
        const int col = bn + wn * 32 + nf * 16 + c0;
        const float s = Sw[col];
        #pragma unroll
        for (int mf = 0; mf < 4; ++mf) {
            const int rowb = bm + wm * 64 + mf * 16 + r0;
            #pragma unroll
            for (int j = 0; j < 4; ++j)
                Out[(size_t)(rowb + j) * N_DIM + col] = (float)acc[mf][nf][j] * s * Ra[rowb + j];
        }
    }
}

// ---------------- Fallback (fused bf16, if ws too small) ----------------

constexpr int FBM = 128, FBN = 128, FBK = 64, FPAD = 8;

__global__ __launch_bounds__(256)
void qlinear_fused_kernel(const float* __restrict__ A, const int* __restrict__ Wqi,
                          const float* __restrict__ Sw, float* __restrict__ Out, int M) {
    __shared__ unsigned short Asf[FBM][FBK + FPAD];
    __shared__ unsigned short Bsf[FBN][FBK + FPAD];
    const int tid  = threadIdx.x;
    const int lane = tid & 63;
    const int wid  = tid >> 6;
    const int wm   = wid >> 1;
    const int wn   = wid & 1;
    const int bm = blockIdx.y * FBM;
    const int bn = blockIdx.x * FBN;
    const int rowT = tid >> 4;
    const int kq   = tid & 15;
    f32x4 acc[4][4];
    #pragma unroll
    for (int i = 0; i < 4; ++i)
        #pragma unroll
        for (int j = 0; j < 4; ++j) acc[i][j] = (f32x4){0.f,0.f,0.f,0.f};
    const int c0 = lane & 15;
    const int kg = (lane >> 4) * 8;
    for (int k0 = 0; k0 < K_DIM; k0 += FBK) {
        #pragma unroll
        for (int it = 0; it < 8; ++it) {
            const int r = it * 16 + rowT;
            const f32x4 a4 = *(const f32x4*)(A + (size_t)(bm + r) * K_DIM + k0 + kq * 4);
            u16x4 h;
            h[0]=f32_to_bf16(a4[0]); h[1]=f32_to_bf16(a4[1]);
            h[2]=f32_to_bf16(a4[2]); h[3]=f32_to_bf16(a4[3]);
            *(u16x4*)&Asf[r][kq*4] = h;
        }
        #pragma unroll
        for (int it = 0; it < 8; ++it) {
            const int r = it * 16 + rowT;
            const i32x4 w4 = *(const i32x4*)(Wqi + (size_t)(bn + r) * K_DIM + k0 + kq * 4);
            u16x4 h;
            h[0]=f32_to_bf16((float)w4[0]); h[1]=f32_to_bf16((float)w4[1]);
            h[2]=f32_to_bf16((float)w4[2]); h[3]=f32_to_bf16((float)w4[3]);
            *(u16x4*)&Bsf[r][kq*4] = h;
        }
        __syncthreads();
        #pragma unroll
        for (int ks = 0; ks < 2; ++ks) {
            const int kk = ks * 32 + kg;
            bf16x8 af2[4], bfr[4];
            #pragma unroll
            for (int mf = 0; mf < 4; ++mf)
                af2[mf] = *(const bf16x8*)&Asf[wm*64 + mf*16 + c0][kk];
            #pragma unroll
            for (int nf = 0; nf < 4; ++nf)
                bfr[nf] = *(const bf16x8*)&Bsf[wn*64 + nf*16 + c0][kk];
            #pragma unroll
            for (int mf = 0; mf < 4; ++mf)
                #pragma unroll
                for (int nf = 0; nf < 4; ++nf)
                    acc[mf][nf] = __builtin_amdgcn_mfma_f32_16x16x32_bf16(
                        af2[mf], bfr[nf], acc[mf][nf], 0, 0, 0);
        }
        __syncthreads();
    }
    const int r0 = (lane >> 4) * 4;
    #pragma unroll
    for (int nf = 0; nf < 4; ++nf) {
        const int col = bn + wn*64 + nf*16 + c0;
        const float s = Sw[col];
        #pragma unroll
        for (int mf = 0; mf < 4; ++mf) {
            const int rowb = bm + wm*64 + mf*16 + r0;
            #pragma unroll
            for (int j = 0; j < 4; ++j)
                Out[(size_t)(rowb + j) * N_DIM + col] = acc[mf][nf][j] * s;
        }
    }
}

extern "C" void kernel_launch(void* const* d_in, const int* in_sizes, int n_in,
                              void* d_out, int out_size, void* d_ws, size_t ws_size,
                              hipStream_t stream) {
    const float* inp = (const float*)d_in[0];
    const int*   qw  = (const int*)d_in[1];
    const float* sw  = (const float*)d_in[2];
    float*       out = (float*)d_out;

    const int M = in_sizes[0] / K_DIM;                         // 4096
    const size_t nA = (size_t)M * K_DIM;                       // A elements
    const size_t nW = (size_t)N_DIM * K_DIM;                   // W elements
    const size_t needQ = nA + nW + (size_t)M * sizeof(float);  // ~67 MiB

    if (ws_size >= needQ && (M % BM) == 0) {
        signed char* Apk = (signed char*)d_ws;
        signed char* Wpk = Apk + nA;
        float*       Ra  = (float*)(Wpk + nW);
        quant_a_pack<<<M, 256, 0, stream>>>(inp, Apk, Ra);
        pack_w_kernel<<<2048, 256, 0, stream>>>(qw, Wpk, (int)(nW / 16));
        dim3 grid((N_DIM / BN) * (M / BM));                    // 3072
        gemm_i8_nolds<<<grid, 512, 0, stream>>>(Apk, Wpk, sw, Ra, out, M);
    } else {
        dim3 grid(N_DIM / FBN, M / FBM);
        qlinear_fused_kernel<<<grid, 256, 0, stream>>>(inp, qw, sw, out, M);
    }
}